// Round 4
// baseline (151.934 us; speedup 1.0000x reference)
//
#include <hip/hip_runtime.h>

// Problem constants
// B=2, L=256, D=512, H=8, Dh=64, NUM_RADIAL=64, N_SPH=9, F=576
#define NB 2
#define NL 256
#define ND 512
#define NH 8
#define NDH 64
#define NR 64
#define NS 9
#define NF 576
#define NHS 72   // NH*NS
#define WQROW 4608  // NH*NF = NR*NHS

__device__ __forceinline__ float block_sum(float v, float* s_red) {
    #pragma unroll
    for (int off = 32; off; off >>= 1) v += __shfl_xor(v, off, 64);
    __syncthreads();  // protect s_red from previous use
    if ((threadIdx.x & 63) == 0) s_red[threadIdx.x >> 6] = v;
    __syncthreads();
    return s_red[0] + s_red[1] + s_red[2] + s_red[3];
}

// ---------------------------------------------------------------------------
// K1: Wq[row][h*576 + s*64 + r] = sum_d rp_w[(s*64+r)][h*64+d] * src[row][h*64+d]
// grid (64 rowtiles of 8, 8 heads), 256 threads.
// rp_w staged through LDS (coalesced, XOR-swizzled b128); stores coalesced.
// Layout note: Wq row is stored [h][s][r] but consumed r-major in K2 via
// strided SGPR loads -- K2 reads wq4[(r*18)+j] from a [r][hs] view, so K1
// writes transposed: index h*NF+s*64+ff maps to [r=ff][hs=h*9+s] below.
// ---------------------------------------------------------------------------
__global__ __launch_bounds__(256) void k1_wq(const float* __restrict__ src,
                                             const float* __restrict__ rp_w,
                                             float* __restrict__ Wq) {
    int rt = blockIdx.x;   // 64 rowtiles x 8 rows
    int h  = blockIdx.y;
    int t  = threadIdx.x;
    __shared__ float s_src[8][64];   // 2 KB
    __shared__ float s_B[64 * 64];   // 16 KB, slot-swizzled rows
    int r0 = rt * 8;
    {   // stage src tile: 8 rows x 64 d, float2 per thread, coalesced
        int sr = t >> 5;
        int sc = (t & 31) * 2;
        *(float2*)&s_src[sr][sc] =
            *(const float2*)(src + (size_t)(r0 + sr) * ND + h * 64 + sc);
    }
    int ff = t & 63;        // = r index of output
    int g  = t >> 6;        // wave id 0..3 -> rows 2g, 2g+1
    int lr = t >> 2;        // loader row 0..63
    int lq = t & 3;         // loader quarter
    const float* bsrc = rp_w + h * 64;

    #pragma unroll 1
    for (int s = 0; s < NS; ++s) {
        __syncthreads();   // protect s_B (and s_src on first iter)
        // stage chunk s: s_B[row][slot^(row&7)] <- rp_w[(s*64+row)*512 + h*64 ...]
        #pragma unroll
        for (int i = 0; i < 4; ++i) {
            int slot = i * 4 + lq;                 // 0..15, lanes consecutive
            float4 v = *(const float4*)(bsrc + (size_t)(s * 64 + lr) * ND + slot * 4);
            int sw = slot ^ (lr & 7);
            *(float4*)&s_B[lr * 64 + sw * 4] = v;
        }
        __syncthreads();
        float a0 = 0.f, a1 = 0.f;
        #pragma unroll
        for (int d4 = 0; d4 < 16; ++d4) {
            int sw = d4 ^ (ff & 7);
            float4 bv = *(const float4*)&s_B[ff * 64 + sw * 4];
            float4 s0 = *(const float4*)&s_src[2 * g][d4 * 4];
            float4 s1 = *(const float4*)&s_src[2 * g + 1][d4 * 4];
            a0 = fmaf(bv.x, s0.x, a0);
            a0 = fmaf(bv.y, s0.y, a0);
            a0 = fmaf(bv.z, s0.z, a0);
            a0 = fmaf(bv.w, s0.w, a0);
            a1 = fmaf(bv.x, s1.x, a1);
            a1 = fmaf(bv.y, s1.y, a1);
            a1 = fmaf(bv.z, s1.z, a1);
            a1 = fmaf(bv.w, s1.w, a1);
        }
        // store transposed for K2: [r=ff][hs=h*9+s], lanes ff -> stride NHS
        Wq[(size_t)(r0 + 2 * g) * WQROW + ff * NHS + h * NS + s] = a0;
        Wq[(size_t)(r0 + 2 * g + 1) * WQROW + ff * NHS + h * NS + s] = a1;
    }
}

// ---------------------------------------------------------------------------
// K2: per (b,l) row: logits = qk/8 + rp_scores, softmax over m, V-accum,
//     residual + LayerNorm1 -> x1buf.
// r-outer rp contraction with Wq row read through a WAVE-UNIFORM global
// pointer -> compiler emits s_load into SGPRs (zero VALU/LDS-port cost);
// v_fmac takes the SGPR operand directly. 72 accumulators stay in VGPRs
// (launch_bounds(256,2) -> 256-VGPR budget, no spill). rbf recomputed
// inline per r (64 exp total, no rbf[] array).
// ---------------------------------------------------------------------------
__global__ __launch_bounds__(256, 2) void k2_attn(const float* __restrict__ src,
                                                  const float* __restrict__ rel_diss,
                                                  const float* __restrict__ rel_dirs,
                                                  const float* __restrict__ Wq,
                                                  const float* __restrict__ gamma1,
                                                  const float* __restrict__ beta1,
                                                  float* __restrict__ x1buf) {
    int row = blockIdx.x;      // b*256 + l
    int b = row >> 8;
    int m = threadIdx.x;
    __shared__ float s_w[NH][NL];   // 8 KB: logits -> softmax weights
    __shared__ float s_red[8];

    // --- radial basis inputs + spherical harmonics for (l, m) pair ---
    float dist = rel_diss[(size_t)row * NL + m];
    const float* dirp = rel_dirs + ((size_t)row * NL + m) * 3;
    float x = dirp[0], y = dirp[1], z = dirp[2];
    float tcl = fminf(fmaxf(dist * 0.1f, 0.f), 1.f);
    float env = 0.5f * (__cosf(3.14159265358979f * tcl) + 1.f);
    float sph[NS];
    sph[0] = 0.28209479177387814f;
    sph[1] = 0.4886025119029199f * y;
    sph[2] = 0.4886025119029199f * z;
    sph[3] = 0.4886025119029199f * x;
    sph[4] = 1.0925484305920792f * x * y;
    sph[5] = 1.0925484305920792f * y * z;
    sph[6] = 0.31539156525252005f * (3.f * z * z - 1.f);
    sph[7] = 1.0925484305920792f * x * z;
    sph[8] = 0.5462742152960396f * (x * x - y * y);

    // --- rp contraction, r-outer: acc[hs] += wq[r][hs] * rbf_r ---
    // wq4 is wave-uniform; all offsets compile-time -> scalar s_load path.
    const float4* __restrict__ wq4 = (const float4*)(Wq + (size_t)row * WQROW);
    float acc[NHS];
    #pragma unroll
    for (int i = 0; i < NHS; ++i) acc[i] = 0.f;
    #pragma unroll 2
    for (int r = 0; r < NR; ++r) {
        float c = r * (10.f / 63.f);
        float df = dist - c;
        float rbf_r = __expf(-df * df * 20.48f) * env;   // 1/(2*width^2)=20.48
        #pragma unroll
        for (int j = 0; j < 18; ++j) {
            float4 wv = wq4[r * 18 + j];                 // uniform -> SGPR
            acc[j * 4 + 0] = fmaf(wv.x, rbf_r, acc[j * 4 + 0]);
            acc[j * 4 + 1] = fmaf(wv.y, rbf_r, acc[j * 4 + 1]);
            acc[j * 4 + 2] = fmaf(wv.z, rbf_r, acc[j * 4 + 2]);
            acc[j * 4 + 3] = fmaf(wv.w, rbf_r, acc[j * 4 + 3]);
        }
    }

    // --- per-head: reduce over s with sph, add qk/8, write logits ---
    const float* qrow = src + (size_t)row * ND;   // uniform -> s_load
    const float4* k4p = (const float4*)(src + ((size_t)b * NL + m) * ND);
    #pragma unroll
    for (int h = 0; h < NH; ++h) {
        float sc = 0.f;
        #pragma unroll
        for (int s = 0; s < NS; ++s) sc = fmaf(sph[s], acc[h * NS + s], sc);
        float qa0 = 0.f, qa1 = 0.f, qa2 = 0.f, qa3 = 0.f;
        #pragma unroll
        for (int dq = 0; dq < 16; dq += 4) {
            float4 kv0 = k4p[h * 16 + dq + 0];
            float4 kv1 = k4p[h * 16 + dq + 1];
            float4 kv2 = k4p[h * 16 + dq + 2];
            float4 kv3 = k4p[h * 16 + dq + 3];
            qa0 = fmaf(qrow[h * 64 + dq * 4 + 0], kv0.x, qa0);
            qa0 = fmaf(qrow[h * 64 + dq * 4 + 1], kv0.y, qa0);
            qa0 = fmaf(qrow[h * 64 + dq * 4 + 2], kv0.z, qa0);
            qa0 = fmaf(qrow[h * 64 + dq * 4 + 3], kv0.w, qa0);
            qa1 = fmaf(qrow[h * 64 + dq * 4 + 4], kv1.x, qa1);
            qa1 = fmaf(qrow[h * 64 + dq * 4 + 5], kv1.y, qa1);
            qa1 = fmaf(qrow[h * 64 + dq * 4 + 6], kv1.z, qa1);
            qa1 = fmaf(qrow[h * 64 + dq * 4 + 7], kv1.w, qa1);
            qa2 = fmaf(qrow[h * 64 + dq * 4 + 8], kv2.x, qa2);
            qa2 = fmaf(qrow[h * 64 + dq * 4 + 9], kv2.y, qa2);
            qa2 = fmaf(qrow[h * 64 + dq * 4 + 10], kv2.z, qa2);
            qa2 = fmaf(qrow[h * 64 + dq * 4 + 11], kv2.w, qa2);
            qa3 = fmaf(qrow[h * 64 + dq * 4 + 12], kv3.x, qa3);
            qa3 = fmaf(qrow[h * 64 + dq * 4 + 13], kv3.y, qa3);
            qa3 = fmaf(qrow[h * 64 + dq * 4 + 14], kv3.z, qa3);
            qa3 = fmaf(qrow[h * 64 + dq * 4 + 15], kv3.w, qa3);
        }
        s_w[h][m] = sc + ((qa0 + qa1) + (qa2 + qa3)) * 0.125f;
    }
    __syncthreads();

    // --- softmax over m per head: wave w handles heads 2w, 2w+1 ---
    int wv = m >> 6, lane = m & 63;
    #pragma unroll
    for (int hi = 0; hi < 2; ++hi) {
        int hh = wv * 2 + hi;
        float v0 = s_w[hh][lane], v1 = s_w[hh][lane + 64];
        float v2 = s_w[hh][lane + 128], v3 = s_w[hh][lane + 192];
        float mx = fmaxf(fmaxf(v0, v1), fmaxf(v2, v3));
        #pragma unroll
        for (int off = 32; off; off >>= 1) mx = fmaxf(mx, __shfl_xor(mx, off, 64));
        float p0 = __expf(v0 - mx), p1 = __expf(v1 - mx);
        float p2 = __expf(v2 - mx), p3 = __expf(v3 - mx);
        float sm = p0 + p1 + p2 + p3;
        #pragma unroll
        for (int off = 32; off; off >>= 1) sm += __shfl_xor(sm, off, 64);
        float inv = 1.f / sm;
        s_w[hh][lane] = p0 * inv;
        s_w[hh][lane + 64] = p1 * inv;
        s_w[hh][lane + 128] = p2 * inv;
        s_w[hh][lane + 192] = p3 * inv;
    }
    __syncthreads();

    // --- V accumulation: thread t owns dims {2t, 2t+1} ---
    int d0 = m * 2;            // 0..510
    int h0 = m >> 5;           // head index 0..7
    float a0 = 0.f, a1 = 0.f, b0 = 0.f, b1 = 0.f;
    const float* vbase = src + (size_t)b * NL * ND;
    #pragma unroll 4
    for (int mm = 0; mm < NL; mm += 2) {
        float w0 = s_w[h0][mm];
        float w1 = s_w[h0][mm + 1];
        float2 v0 = *(const float2*)(vbase + (size_t)mm * ND + d0);
        float2 v1 = *(const float2*)(vbase + (size_t)(mm + 1) * ND + d0);
        a0 = fmaf(w0, v0.x, a0);
        a1 = fmaf(w0, v0.y, a1);
        b0 = fmaf(w1, v1.x, b0);
        b1 = fmaf(w1, v1.y, b1);
    }
    a0 += b0;
    a1 += b1;
    // residual + LayerNorm1 (2 elements per thread)
    float2 s0 = *(const float2*)(qrow + d0);
    float x0 = s0.x + a0, x1v = s0.y + a1;
    float mu = block_sum(x0 + x1v, s_red) * (1.f / 512.f);
    float e0 = x0 - mu, e1 = x1v - mu;
    float var = block_sum(e0 * e0 + e1 * e1, s_red) * (1.f / 512.f);
    float rs = rsqrtf(var + 1e-5f);
    float2 g0 = *(const float2*)(gamma1 + d0), be0 = *(const float2*)(beta1 + d0);
    float* o = x1buf + (size_t)row * ND;
    *(float2*)(o + d0) = make_float2(e0 * rs * g0.x + be0.x, e1 * rs * g0.y + be0.y);
}

// ---------------------------------------------------------------------------
// K3: hbuf = leaky_relu(x1 @ w1 + b1)  [512,512]@[512,2048]
// 32x64 tile, 2x4 microtile, BK=16; grid 32x16 = 512 blocks (2/CU)
// ---------------------------------------------------------------------------
__global__ __launch_bounds__(256) void k3_ffn1(const float* __restrict__ A,
                                               const float* __restrict__ Bw,
                                               const float* __restrict__ bias,
                                               float* __restrict__ C) {
    const int N = 2048, K = 512;
    int n0 = blockIdx.x * 64, m0 = blockIdx.y * 32;
    int t = threadIdx.x;
    int tx = t & 15, ty = t >> 4;          // 16 x 16
    __shared__ float As[16][34];
    __shared__ float Bs[16][64];
    float acc[2][4] = {};
    int am = t >> 3, ak = (t & 7) * 2;     // A loader: 32 rows x 16 k (float2)
    int bk = t >> 4, bn = (t & 15) * 4;    // B loader: 16 rows x 64 n (float4)
    for (int k0 = 0; k0 < K; k0 += 16) {
        float2 av = *(const float2*)(A + (size_t)(m0 + am) * K + k0 + ak);
        float4 bv = *(const float4*)(Bw + (size_t)(k0 + bk) * N + n0 + bn);
        __syncthreads();
        As[ak][am] = av.x;
        As[ak + 1][am] = av.y;
        *(float4*)&Bs[bk][bn] = bv;
        __syncthreads();
        #pragma unroll
        for (int k = 0; k < 16; ++k) {
            float2 a = *(const float2*)&As[k][ty * 2];
            float4 bb = *(const float4*)&Bs[k][tx * 4];
            acc[0][0] = fmaf(a.x, bb.x, acc[0][0]);
            acc[0][1] = fmaf(a.x, bb.y, acc[0][1]);
            acc[0][2] = fmaf(a.x, bb.z, acc[0][2]);
            acc[0][3] = fmaf(a.x, bb.w, acc[0][3]);
            acc[1][0] = fmaf(a.y, bb.x, acc[1][0]);
            acc[1][1] = fmaf(a.y, bb.y, acc[1][1]);
            acc[1][2] = fmaf(a.y, bb.z, acc[1][2]);
            acc[1][3] = fmaf(a.y, bb.w, acc[1][3]);
        }
    }
    #pragma unroll
    for (int i = 0; i < 2; ++i) {
        int rrow = m0 + ty * 2 + i;
        int cc = n0 + tx * 4;
        float v0 = acc[i][0] + bias[cc + 0];
        float v1 = acc[i][1] + bias[cc + 1];
        float v2 = acc[i][2] + bias[cc + 2];
        float v3 = acc[i][3] + bias[cc + 3];
        float4 ov;
        ov.x = v0 >= 0.f ? v0 : 0.01f * v0;
        ov.y = v1 >= 0.f ? v1 : 0.01f * v1;
        ov.z = v2 >= 0.f ? v2 : 0.01f * v2;
        ov.w = v3 >= 0.f ? v3 : 0.01f * v3;
        *(float4*)(C + (size_t)rrow * N + cc) = ov;
    }
}

// ---------------------------------------------------------------------------
// K4: zpart[ks] = hbuf[:, ks*512:(ks+1)*512] @ w2[ks*512:(ks+1)*512, :]
// 32x64 tile, 2x4 microtile, split-K=4; grid 8x16x4 = 512 blocks
// ---------------------------------------------------------------------------
__global__ __launch_bounds__(256) void k4_ffn2(const float* __restrict__ A,
                                               const float* __restrict__ Bw,
                                               float* __restrict__ Cp) {
    const int N = 512, K = 2048;
    int n0 = blockIdx.x * 64, m0 = blockIdx.y * 32;
    int ks = blockIdx.z;
    int t = threadIdx.x;
    int tx = t & 15, ty = t >> 4;
    __shared__ float As[16][34];
    __shared__ float Bs[16][64];
    float acc[2][4] = {};
    int am = t >> 3, ak = (t & 7) * 2;
    int bk = t >> 4, bn = (t & 15) * 4;
    int kbase = ks * 512;
    for (int k0 = kbase; k0 < kbase + 512; k0 += 16) {
        float2 av = *(const float2*)(A + (size_t)(m0 + am) * K + k0 + ak);
        float4 bv = *(const float4*)(Bw + (size_t)(k0 + bk) * N + n0 + bn);
        __syncthreads();
        As[ak][am] = av.x;
        As[ak + 1][am] = av.y;
        *(float4*)&Bs[bk][bn] = bv;
        __syncthreads();
        #pragma unroll
        for (int k = 0; k < 16; ++k) {
            float2 a = *(const float2*)&As[k][ty * 2];
            float4 bb = *(const float4*)&Bs[k][tx * 4];
            acc[0][0] = fmaf(a.x, bb.x, acc[0][0]);
            acc[0][1] = fmaf(a.x, bb.y, acc[0][1]);
            acc[0][2] = fmaf(a.x, bb.z, acc[0][2]);
            acc[0][3] = fmaf(a.x, bb.w, acc[0][3]);
            acc[1][0] = fmaf(a.y, bb.x, acc[1][0]);
            acc[1][1] = fmaf(a.y, bb.y, acc[1][1]);
            acc[1][2] = fmaf(a.y, bb.z, acc[1][2]);
            acc[1][3] = fmaf(a.y, bb.w, acc[1][3]);
        }
    }
    float* out = Cp + ((size_t)ks << 18);
    #pragma unroll
    for (int i = 0; i < 2; ++i) {
        int rrow = m0 + ty * 2 + i;
        int cc = n0 + tx * 4;
        *(float4*)(out + (size_t)rrow * N + cc) =
            make_float4(acc[i][0], acc[i][1], acc[i][2], acc[i][3]);
    }
}

// ---------------------------------------------------------------------------
// K5: z = x1 + b2 + sum_ks zpart[ks]; out = LayerNorm2(z)
// ---------------------------------------------------------------------------
__global__ __launch_bounds__(256) void k5_final(const float* __restrict__ x1buf,
                                                const float* __restrict__ zpart,
                                                const float* __restrict__ b2,
                                                const float* __restrict__ gamma2,
                                                const float* __restrict__ beta2,
                                                float* __restrict__ out) {
    int row = blockIdx.x;
    int t = threadIdx.x;
    int d0 = t * 2;
    __shared__ float s_red[8];
    size_t off = (size_t)row * ND + d0;
    float2 v = *(const float2*)(x1buf + off);
    float2 bb = *(const float2*)(b2 + d0);
    float z0 = v.x + bb.x, z1 = v.y + bb.y;
    #pragma unroll
    for (int ks = 0; ks < 4; ++ks) {
        float2 p = *(const float2*)(zpart + ((size_t)ks << 18) + off);
        z0 += p.x;
        z1 += p.y;
    }
    float mu = block_sum(z0 + z1, s_red) * (1.f / 512.f);
    float e0 = z0 - mu, e1 = z1 - mu;
    float var = block_sum(e0 * e0 + e1 * e1, s_red) * (1.f / 512.f);
    float rs = rsqrtf(var + 1e-5f);
    float2 g = *(const float2*)(gamma2 + d0), be = *(const float2*)(beta2 + d0);
    *(float2*)(out + off) = make_float2(e0 * rs * g.x + be.x, e1 * rs * g.y + be.y);
}

// ---------------------------------------------------------------------------
extern "C" void kernel_launch(void* const* d_in, const int* in_sizes, int n_in,
                              void* d_out, int out_size, void* d_ws, size_t ws_size,
                              hipStream_t stream) {
    const float* src      = (const float*)d_in[0];
    const float* rel_diss = (const float*)d_in[1];
    const float* rel_dirs = (const float*)d_in[2];
    const float* rp_w     = (const float*)d_in[3];
    // d_in[4] = rp_b: constant over softmax axis -> cancels exactly; skipped
    const float* w1  = (const float*)d_in[5];
    const float* b1  = (const float*)d_in[6];
    const float* w2  = (const float*)d_in[7];
    const float* b2  = (const float*)d_in[8];
    const float* g1  = (const float*)d_in[9];
    const float* be1 = (const float*)d_in[10];
    const float* g2  = (const float*)d_in[11];
    const float* be2 = (const float*)d_in[12];
    float* out = (float*)d_out;

    float* ws = (float*)d_ws;
    float* x1buf = ws;                       // 512*512        = 262144
    float* hbuf  = x1buf + 262144;           // 512*2048       = 1048576
    float* zpart = hbuf + 1048576;           // 4*512*512      = 1048576
    float* Wq    = zpart + 1048576;          // 512*4608       = 2359296
    // total 4,718,592 floats = 18 MiB of d_ws

    k1_wq<<<dim3(64, 8), 256, 0, stream>>>(src, rp_w, Wq);
    k2_attn<<<dim3(512), 256, 0, stream>>>(src, rel_diss, rel_dirs, Wq, g1, be1, x1buf);
    k3_ffn1<<<dim3(32, 16), 256, 0, stream>>>(x1buf, w1, b1, hbuf);
    k4_ffn2<<<dim3(8, 16, 4), 256, 0, stream>>>(hbuf, w2, zpart);
    k5_final<<<dim3(512), 256, 0, stream>>>(x1buf, zpart, b2, g2, be2, out);
}

// Round 5
// 134.941 us; speedup vs baseline: 1.1259x; 1.1259x over previous
//
#include <hip/hip_runtime.h>

// Problem constants
// B=2, L=256, D=512, H=8, Dh=64, NUM_RADIAL=64, N_SPH=9, F=576
#define NB 2
#define NL 256
#define ND 512
#define NH 8
#define NDH 64
#define NR 64
#define NS 9
#define NF 576
#define NHS 72      // NH*NS
#define WQROW 4608  // NR*NHS
#define WQPAD 84    // LDS row stride for s_wq: 84 mod 32 = 20, gcd(20,32)=4 ->
                    // r mod 8 covers all 8 bank-quads -> near-conflict-free
#define RWIN 12     // rbf window: terms beyond 5.5*delta < 2e-7 -> negligible

__device__ __forceinline__ float block_sum(float v, float* s_red) {
    #pragma unroll
    for (int off = 32; off; off >>= 1) v += __shfl_xor(v, off, 64);
    __syncthreads();  // protect s_red from previous use
    if ((threadIdx.x & 63) == 0) s_red[threadIdx.x >> 6] = v;
    __syncthreads();
    return s_red[0] + s_red[1] + s_red[2] + s_red[3];
}

// ---------------------------------------------------------------------------
// K1: Wq[row][r*72 + h*9+s] = sum_d rp_w[(s*64+r)][h*64+d] * src[row][h*64+d]
// grid (64 rowtiles of 8, 8 heads), 256 threads.
// ---------------------------------------------------------------------------
__global__ __launch_bounds__(256) void k1_wq(const float* __restrict__ src,
                                             const float* __restrict__ rp_w,
                                             float* __restrict__ Wq) {
    int rt = blockIdx.x;   // 64 rowtiles x 8 rows
    int h  = blockIdx.y;
    int t  = threadIdx.x;
    __shared__ float s_src[8][64];   // 2 KB
    __shared__ float s_B[64 * 64];   // 16 KB, slot-swizzled rows
    int r0 = rt * 8;
    {   // stage src tile: 8 rows x 64 d, float2 per thread, coalesced
        int sr = t >> 5;
        int sc = (t & 31) * 2;
        *(float2*)&s_src[sr][sc] =
            *(const float2*)(src + (size_t)(r0 + sr) * ND + h * 64 + sc);
    }
    int ff = t & 63;        // = r index of output
    int g  = t >> 6;        // wave id 0..3 -> rows 2g, 2g+1
    int lr = t >> 2;        // loader row 0..63
    int lq = t & 3;         // loader quarter
    const float* bsrc = rp_w + h * 64;

    #pragma unroll 1
    for (int s = 0; s < NS; ++s) {
        __syncthreads();   // protect s_B (and s_src on first iter)
        #pragma unroll
        for (int i = 0; i < 4; ++i) {
            int slot = i * 4 + lq;                 // 0..15, lanes consecutive
            float4 v = *(const float4*)(bsrc + (size_t)(s * 64 + lr) * ND + slot * 4);
            int sw = slot ^ (lr & 7);
            *(float4*)&s_B[lr * 64 + sw * 4] = v;
        }
        __syncthreads();
        float a0 = 0.f, a1 = 0.f;
        #pragma unroll
        for (int d4 = 0; d4 < 16; ++d4) {
            int sw = d4 ^ (ff & 7);
            float4 bv = *(const float4*)&s_B[ff * 64 + sw * 4];
            float4 s0 = *(const float4*)&s_src[2 * g][d4 * 4];
            float4 s1 = *(const float4*)&s_src[2 * g + 1][d4 * 4];
            a0 = fmaf(bv.x, s0.x, a0);
            a0 = fmaf(bv.y, s0.y, a0);
            a0 = fmaf(bv.z, s0.z, a0);
            a0 = fmaf(bv.w, s0.w, a0);
            a1 = fmaf(bv.x, s1.x, a1);
            a1 = fmaf(bv.y, s1.y, a1);
            a1 = fmaf(bv.z, s1.z, a1);
            a1 = fmaf(bv.w, s1.w, a1);
        }
        // store [r=ff][hs=h*9+s]
        Wq[(size_t)(r0 + 2 * g) * WQROW + ff * NHS + h * NS + s] = a0;
        Wq[(size_t)(r0 + 2 * g + 1) * WQROW + ff * NHS + h * NS + s] = a1;
    }
}

// ---------------------------------------------------------------------------
// K2: per (b,l) row: logits = qk/8 + rp_scores, softmax over m, V-accum,
//     residual + LayerNorm1 -> x1buf.
// Wq row staged in LDS [64 r][84]; each thread reads only its 12-r window
// (gaussian rbf support) via per-lane ds_read_b128. hs processed in 4 chunks
// of 20 accumulators (compiler-friendly). env folded into sph.
// ---------------------------------------------------------------------------
__global__ __launch_bounds__(256, 2) void k2_attn(const float* __restrict__ src,
                                                  const float* __restrict__ rel_diss,
                                                  const float* __restrict__ rel_dirs,
                                                  const float* __restrict__ Wq,
                                                  const float* __restrict__ gamma1,
                                                  const float* __restrict__ beta1,
                                                  float* __restrict__ x1buf) {
    int row = blockIdx.x;      // b*256 + l
    int b = row >> 8;
    int m = threadIdx.x;
    __shared__ float s_wq[NR * WQPAD];  // 21 KB
    __shared__ float s_w[NH][NL];       // 8 KB: logits -> softmax weights
    __shared__ float s_red[8];

    // --- stage Wq row into LDS (coalesced read, padded rows) ---
    const float* wrow = Wq + (size_t)row * WQROW;
    #pragma unroll
    for (int i = 0; i < 18; ++i) {
        int flat = i * 256 + m;          // 0..4607, [r][hs] r-major
        int r = flat / 72, c = flat - 72 * r;
        s_wq[r * WQPAD + c] = wrow[flat];
    }
    #pragma unroll
    for (int i = 0; i < 3; ++i) {        // zero pad cols 72..83
        int p = i * 256 + m;             // 0..767
        int r = p / 12, c = 72 + (p - 12 * r);
        s_wq[r * WQPAD + c] = 0.f;
    }

    // --- rbf window + spherical harmonics (env folded into sph) ---
    float dist = rel_diss[(size_t)row * NL + m];
    const float* dirp = rel_dirs + ((size_t)row * NL + m) * 3;
    float x = dirp[0], y = dirp[1], z = dirp[2];
    float tcl = fminf(fmaxf(dist * 0.1f, 0.f), 1.f);
    float env = 0.5f * (__cosf(3.14159265358979f * tcl) + 1.f);
    int rc = (int)floorf(dist * 6.3f + 0.5f);          // nearest center
    int rlo = min(max(rc - 6, 0), NR - RWIN);          // window [rlo, rlo+12)
    float sph[NS];
    sph[0] = 0.28209479177387814f * env;
    sph[1] = 0.4886025119029199f * y * env;
    sph[2] = 0.4886025119029199f * z * env;
    sph[3] = 0.4886025119029199f * x * env;
    sph[4] = 1.0925484305920792f * x * y * env;
    sph[5] = 1.0925484305920792f * y * z * env;
    sph[6] = 0.31539156525252005f * (3.f * z * z - 1.f) * env;
    sph[7] = 1.0925484305920792f * x * z * env;
    sph[8] = 0.5462742152960396f * (x * x - y * y) * env;

    __syncthreads();

    // --- rp contraction over the 12-r window, 4 chunks of 20 hs ---
    float sc[NH];
    #pragma unroll
    for (int h = 0; h < NH; ++h) sc[h] = 0.f;
    #pragma unroll 1
    for (int ch = 0; ch < 4; ++ch) {
        float acc[20];
        #pragma unroll
        for (int i = 0; i < 20; ++i) acc[i] = 0.f;
        #pragma unroll 4
        for (int rw = 0; rw < RWIN; ++rw) {
            int r = rlo + rw;
            float df = dist - r * (10.f / 63.f);
            float rbf = __expf(-df * df * 20.48f);   // 1/(2*width^2)
            const float* wp = &s_wq[r * WQPAD + ch * 20];
            #pragma unroll
            for (int q = 0; q < 5; ++q) {
                float4 w = *(const float4*)(wp + q * 4);
                acc[q * 4 + 0] = fmaf(w.x, rbf, acc[q * 4 + 0]);
                acc[q * 4 + 1] = fmaf(w.y, rbf, acc[q * 4 + 1]);
                acc[q * 4 + 2] = fmaf(w.z, rbf, acc[q * 4 + 2]);
                acc[q * 4 + 3] = fmaf(w.w, rbf, acc[q * 4 + 3]);
            }
        }
        // fold chunk into per-head scores (compile-time indices)
        #pragma unroll
        for (int i = 0; i < 20; ++i) {
            int hs = ch * 20 + i;
            if (hs < NHS) {
                int h = hs / 9, s = hs - 9 * h;
                sc[h] = fmaf(sph[s], acc[i], sc[h]);
            }
        }
    }

    // --- per-head qk/8 + logits ---
    const float* qrow = src + (size_t)row * ND;   // wave-uniform
    const float4* k4p = (const float4*)(src + ((size_t)b * NL + m) * ND);
    #pragma unroll
    for (int h = 0; h < NH; ++h) {
        float qa0 = 0.f, qa1 = 0.f, qa2 = 0.f, qa3 = 0.f;
        #pragma unroll
        for (int dq = 0; dq < 16; dq += 4) {
            float4 kv0 = k4p[h * 16 + dq + 0];
            float4 kv1 = k4p[h * 16 + dq + 1];
            float4 kv2 = k4p[h * 16 + dq + 2];
            float4 kv3 = k4p[h * 16 + dq + 3];
            qa0 = fmaf(qrow[h * 64 + dq * 4 + 0], kv0.x, qa0);
            qa0 = fmaf(qrow[h * 64 + dq * 4 + 1], kv0.y, qa0);
            qa0 = fmaf(qrow[h * 64 + dq * 4 + 2], kv0.z, qa0);
            qa0 = fmaf(qrow[h * 64 + dq * 4 + 3], kv0.w, qa0);
            qa1 = fmaf(qrow[h * 64 + dq * 4 + 4], kv1.x, qa1);
            qa1 = fmaf(qrow[h * 64 + dq * 4 + 5], kv1.y, qa1);
            qa1 = fmaf(qrow[h * 64 + dq * 4 + 6], kv1.z, qa1);
            qa1 = fmaf(qrow[h * 64 + dq * 4 + 7], kv1.w, qa1);
            qa2 = fmaf(qrow[h * 64 + dq * 4 + 8], kv2.x, qa2);
            qa2 = fmaf(qrow[h * 64 + dq * 4 + 9], kv2.y, qa2);
            qa2 = fmaf(qrow[h * 64 + dq * 4 + 10], kv2.z, qa2);
            qa2 = fmaf(qrow[h * 64 + dq * 4 + 11], kv2.w, qa2);
            qa3 = fmaf(qrow[h * 64 + dq * 4 + 12], kv3.x, qa3);
            qa3 = fmaf(qrow[h * 64 + dq * 4 + 13], kv3.y, qa3);
            qa3 = fmaf(qrow[h * 64 + dq * 4 + 14], kv3.z, qa3);
            qa3 = fmaf(qrow[h * 64 + dq * 4 + 15], kv3.w, qa3);
        }
        s_w[h][m] = sc[h] + ((qa0 + qa1) + (qa2 + qa3)) * 0.125f;
    }
    __syncthreads();

    // --- softmax over m per head: wave w handles heads 2w, 2w+1 ---
    int wv = m >> 6, lane = m & 63;
    #pragma unroll
    for (int hi = 0; hi < 2; ++hi) {
        int hh = wv * 2 + hi;
        float v0 = s_w[hh][lane], v1 = s_w[hh][lane + 64];
        float v2 = s_w[hh][lane + 128], v3 = s_w[hh][lane + 192];
        float mx = fmaxf(fmaxf(v0, v1), fmaxf(v2, v3));
        #pragma unroll
        for (int off = 32; off; off >>= 1) mx = fmaxf(mx, __shfl_xor(mx, off, 64));
        float p0 = __expf(v0 - mx), p1 = __expf(v1 - mx);
        float p2 = __expf(v2 - mx), p3 = __expf(v3 - mx);
        float sm = p0 + p1 + p2 + p3;
        #pragma unroll
        for (int off = 32; off; off >>= 1) sm += __shfl_xor(sm, off, 64);
        float inv = 1.f / sm;
        s_w[hh][lane] = p0 * inv;
        s_w[hh][lane + 64] = p1 * inv;
        s_w[hh][lane + 128] = p2 * inv;
        s_w[hh][lane + 192] = p3 * inv;
    }
    __syncthreads();

    // --- V accumulation: thread t owns dims {2t, 2t+1} ---
    int d0 = m * 2;            // 0..510
    int h0 = m >> 5;           // head index 0..7
    float a0 = 0.f, a1 = 0.f, b0 = 0.f, b1 = 0.f;
    const float* vbase = src + (size_t)b * NL * ND;
    #pragma unroll 2
    for (int mm = 0; mm < NL; mm += 4) {
        float4 w = *(const float4*)&s_w[h0][mm];
        float2 v0 = *(const float2*)(vbase + (size_t)(mm + 0) * ND + d0);
        float2 v1 = *(const float2*)(vbase + (size_t)(mm + 1) * ND + d0);
        float2 v2 = *(const float2*)(vbase + (size_t)(mm + 2) * ND + d0);
        float2 v3 = *(const float2*)(vbase + (size_t)(mm + 3) * ND + d0);
        a0 = fmaf(w.x, v0.x, a0);
        a1 = fmaf(w.x, v0.y, a1);
        b0 = fmaf(w.y, v1.x, b0);
        b1 = fmaf(w.y, v1.y, b1);
        a0 = fmaf(w.z, v2.x, a0);
        a1 = fmaf(w.z, v2.y, a1);
        b0 = fmaf(w.w, v3.x, b0);
        b1 = fmaf(w.w, v3.y, b1);
    }
    a0 += b0;
    a1 += b1;
    // residual + LayerNorm1 (2 elements per thread)
    float2 s0 = *(const float2*)(qrow + d0);
    float x0 = s0.x + a0, x1v = s0.y + a1;
    float mu = block_sum(x0 + x1v, s_red) * (1.f / 512.f);
    float e0 = x0 - mu, e1 = x1v - mu;
    float var = block_sum(e0 * e0 + e1 * e1, s_red) * (1.f / 512.f);
    float rs = rsqrtf(var + 1e-5f);
    float2 g0 = *(const float2*)(gamma1 + d0), be0 = *(const float2*)(beta1 + d0);
    float* o = x1buf + (size_t)row * ND;
    *(float2*)(o + d0) = make_float2(e0 * rs * g0.x + be0.x, e1 * rs * g0.y + be0.y);
}

// ---------------------------------------------------------------------------
// K3: hbuf = leaky_relu(x1 @ w1 + b1)  [512,512]@[512,2048]
// 32x64 tile, 2x4 microtile, BK=16; grid 32x16 = 512 blocks (2/CU)
// ---------------------------------------------------------------------------
__global__ __launch_bounds__(256) void k3_ffn1(const float* __restrict__ A,
                                               const float* __restrict__ Bw,
                                               const float* __restrict__ bias,
                                               float* __restrict__ C) {
    const int N = 2048, K = 512;
    int n0 = blockIdx.x * 64, m0 = blockIdx.y * 32;
    int t = threadIdx.x;
    int tx = t & 15, ty = t >> 4;          // 16 x 16
    __shared__ float As[16][34];
    __shared__ float Bs[16][64];
    float acc[2][4] = {};
    int am = t >> 3, ak = (t & 7) * 2;     // A loader: 32 rows x 16 k (float2)
    int bk = t >> 4, bn = (t & 15) * 4;    // B loader: 16 rows x 64 n (float4)
    for (int k0 = 0; k0 < K; k0 += 16) {
        float2 av = *(const float2*)(A + (size_t)(m0 + am) * K + k0 + ak);
        float4 bv = *(const float4*)(Bw + (size_t)(k0 + bk) * N + n0 + bn);
        __syncthreads();
        As[ak][am] = av.x;
        As[ak + 1][am] = av.y;
        *(float4*)&Bs[bk][bn] = bv;
        __syncthreads();
        #pragma unroll
        for (int k = 0; k < 16; ++k) {
            float2 a = *(const float2*)&As[k][ty * 2];
            float4 bb = *(const float4*)&Bs[k][tx * 4];
            acc[0][0] = fmaf(a.x, bb.x, acc[0][0]);
            acc[0][1] = fmaf(a.x, bb.y, acc[0][1]);
            acc[0][2] = fmaf(a.x, bb.z, acc[0][2]);
            acc[0][3] = fmaf(a.x, bb.w, acc[0][3]);
            acc[1][0] = fmaf(a.y, bb.x, acc[1][0]);
            acc[1][1] = fmaf(a.y, bb.y, acc[1][1]);
            acc[1][2] = fmaf(a.y, bb.z, acc[1][2]);
            acc[1][3] = fmaf(a.y, bb.w, acc[1][3]);
        }
    }
    #pragma unroll
    for (int i = 0; i < 2; ++i) {
        int rrow = m0 + ty * 2 + i;
        int cc = n0 + tx * 4;
        float v0 = acc[i][0] + bias[cc + 0];
        float v1 = acc[i][1] + bias[cc + 1];
        float v2 = acc[i][2] + bias[cc + 2];
        float v3 = acc[i][3] + bias[cc + 3];
        float4 ov;
        ov.x = v0 >= 0.f ? v0 : 0.01f * v0;
        ov.y = v1 >= 0.f ? v1 : 0.01f * v1;
        ov.z = v2 >= 0.f ? v2 : 0.01f * v2;
        ov.w = v3 >= 0.f ? v3 : 0.01f * v3;
        *(float4*)(C + (size_t)rrow * N + cc) = ov;
    }
}

// ---------------------------------------------------------------------------
// K4: zpart[ks] = hbuf[:, ks*512:(ks+1)*512] @ w2[ks*512:(ks+1)*512, :]
// 32x64 tile, 2x4 microtile, split-K=4; grid 8x16x4 = 512 blocks
// ---------------------------------------------------------------------------
__global__ __launch_bounds__(256) void k4_ffn2(const float* __restrict__ A,
                                               const float* __restrict__ Bw,
                                               float* __restrict__ Cp) {
    const int N = 512, K = 2048;
    int n0 = blockIdx.x * 64, m0 = blockIdx.y * 32;
    int ks = blockIdx.z;
    int t = threadIdx.x;
    int tx = t & 15, ty = t >> 4;
    __shared__ float As[16][34];
    __shared__ float Bs[16][64];
    float acc[2][4] = {};
    int am = t >> 3, ak = (t & 7) * 2;
    int bk = t >> 4, bn = (t & 15) * 4;
    int kbase = ks * 512;
    for (int k0 = kbase; k0 < kbase + 512; k0 += 16) {
        float2 av = *(const float2*)(A + (size_t)(m0 + am) * K + k0 + ak);
        float4 bv = *(const float4*)(Bw + (size_t)(k0 + bk) * N + n0 + bn);
        __syncthreads();
        As[ak][am] = av.x;
        As[ak + 1][am] = av.y;
        *(float4*)&Bs[bk][bn] = bv;
        __syncthreads();
        #pragma unroll
        for (int k = 0; k < 16; ++k) {
            float2 a = *(const float2*)&As[k][ty * 2];
            float4 bb = *(const float4*)&Bs[k][tx * 4];
            acc[0][0] = fmaf(a.x, bb.x, acc[0][0]);
            acc[0][1] = fmaf(a.x, bb.y, acc[0][1]);
            acc[0][2] = fmaf(a.x, bb.z, acc[0][2]);
            acc[0][3] = fmaf(a.x, bb.w, acc[0][3]);
            acc[1][0] = fmaf(a.y, bb.x, acc[1][0]);
            acc[1][1] = fmaf(a.y, bb.y, acc[1][1]);
            acc[1][2] = fmaf(a.y, bb.z, acc[1][2]);
            acc[1][3] = fmaf(a.y, bb.w, acc[1][3]);
        }
    }
    float* out = Cp + ((size_t)ks << 18);
    #pragma unroll
    for (int i = 0; i < 2; ++i) {
        int rrow = m0 + ty * 2 + i;
        int cc = n0 + tx * 4;
        *(float4*)(out + (size_t)rrow * N + cc) =
            make_float4(acc[i][0], acc[i][1], acc[i][2], acc[i][3]);
    }
}

// ---------------------------------------------------------------------------
// K5: z = x1 + b2 + sum_ks zpart[ks]; out = LayerNorm2(z)
// ---------------------------------------------------------------------------
__global__ __launch_bounds__(256) void k5_final(const float* __restrict__ x1buf,
                                                const float* __restrict__ zpart,
                                                const float* __restrict__ b2,
                                                const float* __restrict__ gamma2,
                                                const float* __restrict__ beta2,
                                                float* __restrict__ out) {
    int row = blockIdx.x;
    int t = threadIdx.x;
    int d0 = t * 2;
    __shared__ float s_red[8];
    size_t off = (size_t)row * ND + d0;
    float2 v = *(const float2*)(x1buf + off);
    float2 bb = *(const float2*)(b2 + d0);
    float z0 = v.x + bb.x, z1 = v.y + bb.y;
    #pragma unroll
    for (int ks = 0; ks < 4; ++ks) {
        float2 p = *(const float2*)(zpart + ((size_t)ks << 18) + off);
        z0 += p.x;
        z1 += p.y;
    }
    float mu = block_sum(z0 + z1, s_red) * (1.f / 512.f);
    float e0 = z0 - mu, e1 = z1 - mu;
    float var = block_sum(e0 * e0 + e1 * e1, s_red) * (1.f / 512.f);
    float rs = rsqrtf(var + 1e-5f);
    float2 g = *(const float2*)(gamma2 + d0), be = *(const float2*)(beta2 + d0);
    *(float2*)(out + off) = make_float2(e0 * rs * g.x + be.x, e1 * rs * g.y + be.y);
}

// ---------------------------------------------------------------------------
extern "C" void kernel_launch(void* const* d_in, const int* in_sizes, int n_in,
                              void* d_out, int out_size, void* d_ws, size_t ws_size,
                              hipStream_t stream) {
    const float* src      = (const float*)d_in[0];
    const float* rel_diss = (const float*)d_in[1];
    const float* rel_dirs = (const float*)d_in[2];
    const float* rp_w     = (const float*)d_in[3];
    // d_in[4] = rp_b: constant over softmax axis -> cancels exactly; skipped
    const float* w1  = (const float*)d_in[5];
    const float* b1  = (const float*)d_in[6];
    const float* w2  = (const float*)d_in[7];
    const float* b2  = (const float*)d_in[8];
    const float* g1  = (const float*)d_in[9];
    const float* be1 = (const float*)d_in[10];
    const float* g2  = (const float*)d_in[11];
    const float* be2 = (const float*)d_in[12];
    float* out = (float*)d_out;

    float* ws = (float*)d_ws;
    float* x1buf = ws;                       // 512*512        = 262144
    float* hbuf  = x1buf + 262144;           // 512*2048       = 1048576
    float* zpart = hbuf + 1048576;           // 4*512*512      = 1048576
    float* Wq    = zpart + 1048576;          // 512*4608       = 2359296
    // total 4,718,592 floats = 18 MiB of d_ws

    k1_wq<<<dim3(64, 8), 256, 0, stream>>>(src, rp_w, Wq);
    k2_attn<<<dim3(512), 256, 0, stream>>>(src, rel_diss, rel_dirs, Wq, g1, be1, x1buf);
    k3_ffn1<<<dim3(32, 16), 256, 0, stream>>>(x1buf, w1, b1, hbuf);
    k4_ffn2<<<dim3(8, 16, 4), 256, 0, stream>>>(hbuf, w2, zpart);
    k5_final<<<dim3(512), 256, 0, stream>>>(x1buf, zpart, b2, g2, be2, out);
}